// Round 9
// baseline (503.996 us; speedup 1.0000x reference)
//
#include <hip/hip_runtime.h>

#define D 64          // D_IN == D_OUT
#define D_EDGE 16
#define NEG 0.01f

typedef unsigned int  uint32;
typedef unsigned short ushort16;

// leaky = max(t, 0.01t): exact for both signs, 2 VALU ops
__device__ __forceinline__ float leaky(float v) { return fmaxf(v, NEG * v); }

// fp32 -> bf16 (round-to-nearest-even), and back (exact)
__device__ __forceinline__ ushort16 f2bf(float f) {
    uint32 b = __float_as_uint(f);
    uint32 r = b + 0x7fffu + ((b >> 16) & 1u);
    return (ushort16)(r >> 16);
}
__device__ __forceinline__ float bf2f(ushort16 u) {
    return __uint_as_float(((uint32)u) << 16);
}
__device__ __forceinline__ float bf_lo(uint32 w) { return __uint_as_float(w << 16); }
__device__ __forceinline__ float bf_hi(uint32 w) { return __uint_as_float(w & 0xffff0000u); }
__device__ __forceinline__ uint32 pk(float a, float b) {
    return (uint32)f2bf(a) | ((uint32)f2bf(b) << 16);
}

// ---------------- Kernel 1: per-node precompute (unchanged, proven) ----------
__global__ __launch_bounds__(256) void node_kernel(
    const float* __restrict__ x, const float* __restrict__ W1,
    const float* __restrict__ W2,
    ushort16* __restrict__ Abf, ushort16* __restrict__ xtb, int N_)
{
    __shared__ float xs[64][68];               // 17408 B; reused for output staging
    uint32* sA = (uint32*)&xs[0][0];
    uint32* sX = sA + 64 * 33;

    const int tid = threadIdx.x;
    const int b0  = blockIdx.x * 64;

    for (int idx = tid; idx < 64 * 16; idx += 256) {
        const int rr = idx >> 4, cc = idx & 15;
        float4 v = make_float4(0.f, 0.f, 0.f, 0.f);
        if (b0 + rr < N_) v = ((const float4*)(x + (size_t)(b0 + rr) * D))[cc];
        *(float4*)&xs[rr][cc * 4] = v;
    }
    __syncthreads();

    const int lane = tid & 63;
    const int q    = __builtin_amdgcn_readfirstlane(tid >> 6);

    float4 xr[16];
#pragma unroll
    for (int i = 0; i < 16; i++) xr[i] = *(const float4*)&xs[lane][4 * i];
    __syncthreads();

    float a_prev = 0.f, b_prev = 0.f;
#pragma unroll
    for (int kk = 0; kk < 16; kk++) {
        const int k = q * 16 + kk;
        const float4* w2r = (const float4*)(W2 + (size_t)k * 64);
        const float4* w1r = (const float4*)(W1 + (size_t)k * 80);
        float a = 0.f, b = 0.f;
#pragma unroll
        for (int j = 0; j < 16; j++) {
            float4 w = w2r[j];
            a += xr[j].x * w.x + xr[j].y * w.y + xr[j].z * w.z + xr[j].w * w.w;
            float4 u = w1r[j];
            b += xr[j].x * u.x + xr[j].y * u.y + xr[j].z * u.z + xr[j].w * u.w;
        }
        if (kk & 1) {
            const int pr = k >> 1;
            sX[lane * 33 + pr] = pk(a_prev, a);
            sA[lane * 33 + pr] = pk(b_prev, b);
        } else {
            a_prev = a; b_prev = b;
        }
    }
    __syncthreads();

    uint32* Au = (uint32*)Abf;
    uint32* Xu = (uint32*)xtb;
    const size_t gbase = (size_t)b0 * 32;
    for (int base = tid * 4; base < 2048; base += 1024) {
        const int nn = base >> 5, cc = base & 31;
        if (b0 + nn < N_) {
            const uint32* ra = sA + nn * 33 + cc;
            const uint32* rx = sX + nn * 33 + cc;
            *(uint4*)(Au + gbase + base) = make_uint4(ra[0], ra[1], ra[2], ra[3]);
            *(uint4*)(Xu + gbase + base) = make_uint4(rx[0], rx[1], rx[2], rx[3]);
        }
    }
}

// ---------------- CSR build: fused dual histogram (dst + src) ----------------
// cnt2[0..N) = dst counts, cnt2[N..2N) = src counts
__global__ __launch_bounds__(256) void hist2_kernel(
    const int* __restrict__ dst, const int* __restrict__ src,
    int* __restrict__ cnt2, int N_, int E_)
{
    int i = blockIdx.x * 256 + threadIdx.x;
    if (i < E_) {
        atomicAdd(cnt2 + dst[i], 1);
        atomicAdd(cnt2 + N_ + src[i], 1);
    }
}

// block b reduces cnt[b*1024..+1023] -> part[b]  (over 2N concatenated)
__global__ __launch_bounds__(256) void scan1(
    const int* __restrict__ cnt, int* __restrict__ part, int N2_)
{
    __shared__ int sm[256];
    const int b = blockIdx.x, t = threadIdx.x;
    const int i0 = b * 1024 + t * 4;
    int s = 0;
    if (i0     < N2_) s += cnt[i0];
    if (i0 + 1 < N2_) s += cnt[i0 + 1];
    if (i0 + 2 < N2_) s += cnt[i0 + 2];
    if (i0 + 3 < N2_) s += cnt[i0 + 3];
    sm[t] = s; __syncthreads();
    for (int off = 128; off > 0; off >>= 1) {
        if (t < off) sm[t] += sm[t + off];
        __syncthreads();
    }
    if (t == 0) part[b] = sm[0];
}

// block b: scans raw part[] in LDS (nb<=256) then writes exclusive prefix.
// Result over concatenated array: rowst2[0..N) = dst CSR starts;
// rowst2[N+s] = E + src CSR start (scatter subtracts E).
__global__ __launch_bounds__(256) void scan3(
    const int* __restrict__ cnt, const int* __restrict__ part,
    int* __restrict__ rowst, int N2_, int nb)
{
    __shared__ int sp[256];
    __shared__ int sm[256];
    const int b = blockIdx.x, t = threadIdx.x;

    sp[t] = (t < nb) ? part[t] : 0;
    __syncthreads();
    for (int off = 1; off < 256; off <<= 1) {
        int a = (t >= off) ? sp[t - off] : 0;
        __syncthreads();
        sp[t] += a;
        __syncthreads();
    }
    const int pbase = (b > 0) ? sp[b - 1] : 0;

    const int i0 = b * 1024 + t * 4;
    int c0 = 0, c1 = 0, c2 = 0, c3 = 0;
    if (i0     < N2_) c0 = cnt[i0];
    if (i0 + 1 < N2_) c1 = cnt[i0 + 1];
    if (i0 + 2 < N2_) c2 = cnt[i0 + 2];
    if (i0 + 3 < N2_) c3 = cnt[i0 + 3];
    const int s = c0 + c1 + c2 + c3;
    sm[t] = s; __syncthreads();
    for (int off = 1; off < 256; off <<= 1) {
        int a = (t >= off) ? sm[t - off] : 0;
        __syncthreads();
        sm[t] += a;
        __syncthreads();
    }
    const int base = pbase + (sm[t] - s);
    if (i0     < N2_) rowst[i0]     = base;
    if (i0 + 1 < N2_) rowst[i0 + 1] = base + c0;
    if (i0 + 2 < N2_) rowst[i0 + 2] = base + c0 + c1;
    if (i0 + 3 < N2_) rowst[i0 + 3] = base + c0 + c1 + c2;
}

// ---------------- Scatter: permute edge records into src-sorted order --------
// REC[pos] (48 B = 3 uint4): {ea as 16 bf16 (8 dw)} {src, dst, 0, 0}
// Coalesced ea read; 48 B near-contiguous writes (segment positions are
// contiguous). Gives the edge kernel streamed reads + lane-shared A-rows.
__global__ __launch_bounds__(256) void scatter_kernel(
    const float* __restrict__ edge_attr, const int* __restrict__ src,
    const int* __restrict__ dst, int* __restrict__ srowpos,
    uint4* __restrict__ REC, int E_)
{
    const int e = blockIdx.x * 256 + threadIdx.x;
    if (e >= E_) return;
    const int s = src[e];
    const int d = dst[e];
    const float4* ea = (const float4*)(edge_attr + (size_t)e * D_EDGE);
    float4 q0 = ea[0], q1 = ea[1], q2 = ea[2], q3 = ea[3];

    const int pos = atomicAdd(srowpos + s, 1) - E_;   // src prefix carries +E
    uint4* R = REC + (size_t)pos * 3;
    R[0] = make_uint4(pk(q0.x, q0.y), pk(q0.z, q0.w), pk(q1.x, q1.y), pk(q1.z, q1.w));
    R[1] = make_uint4(pk(q2.x, q2.y), pk(q2.z, q2.w), pk(q3.x, q3.y), pk(q3.z, q3.w));
    R[2] = make_uint4((uint32)s, (uint32)d, 0u, 0u);
}

// ---------------- Kernel 2 (sorted): edge logits, ONE LANE PER EDGE ----------
// Records are src-sorted: consecutive lanes share src (avg degree 12.8), so
// the A-row gather's 64 addresses dedup to ~6 distinct lines per instruction
// in the coalescer — A random-line traffic drops ~10x (the measured 1.4 TB/s
// random-line ceiling was edge's binding constraint, rounds 2-8).
__global__ __launch_bounds__(256) void edge_kernel_sorted(
    const uint4* __restrict__ REC, const float* __restrict__ W1,
    const float* __restrict__ attn, const ushort16* __restrict__ Abf,
    int* __restrict__ rowpos, int2* __restrict__ SP, int E_)
{
    const int i = blockIdx.x * 256 + threadIdx.x;
    if (i >= E_) return;

    uint4 r0 = REC[(size_t)i * 3 + 0];
    uint4 r1 = REC[(size_t)i * 3 + 1];
    uint4 r2 = REC[(size_t)i * 3 + 2];
    const int s = (int)r2.x;
    const int d = (int)r2.y;

    float Ef[16];
    Ef[ 0] = bf_lo(r0.x); Ef[ 1] = bf_hi(r0.x);
    Ef[ 2] = bf_lo(r0.y); Ef[ 3] = bf_hi(r0.y);
    Ef[ 4] = bf_lo(r0.z); Ef[ 5] = bf_hi(r0.z);
    Ef[ 6] = bf_lo(r0.w); Ef[ 7] = bf_hi(r0.w);
    Ef[ 8] = bf_lo(r1.x); Ef[ 9] = bf_hi(r1.x);
    Ef[10] = bf_lo(r1.y); Ef[11] = bf_hi(r1.y);
    Ef[12] = bf_lo(r1.z); Ef[13] = bf_hi(r1.z);
    Ef[14] = bf_lo(r1.w); Ef[15] = bf_hi(r1.w);

    uint32 Ad[32];
    {
        const uint4* Ap = (const uint4*)(Abf + (size_t)s * D);
#pragma unroll
        for (int t = 0; t < 8; t++) *(uint4*)(Ad + 4 * t) = Ap[t];
    }

    float v = 0.f;
#pragma unroll
    for (int j = 0; j < 32; ++j) {
        const float4* w0 = (const float4*)(W1 + (2 * j) * 80 + 64);
        const float4* w1 = (const float4*)(W1 + (2 * j + 1) * 80 + 64);
        float4 p0 = w0[0], p1 = w0[1], p2 = w0[2], p3 = w0[3];
        float4 q0 = w1[0], q1 = w1[1], q2 = w1[2], q3 = w1[3];

        float g0 = bf_lo(Ad[j]);
        float g1 = bf_hi(Ad[j]);

        g0 = fmaf(Ef[ 0], p0.x, g0); g1 = fmaf(Ef[ 0], q0.x, g1);
        g0 = fmaf(Ef[ 1], p0.y, g0); g1 = fmaf(Ef[ 1], q0.y, g1);
        g0 = fmaf(Ef[ 2], p0.z, g0); g1 = fmaf(Ef[ 2], q0.z, g1);
        g0 = fmaf(Ef[ 3], p0.w, g0); g1 = fmaf(Ef[ 3], q0.w, g1);
        g0 = fmaf(Ef[ 4], p1.x, g0); g1 = fmaf(Ef[ 4], q1.x, g1);
        g0 = fmaf(Ef[ 5], p1.y, g0); g1 = fmaf(Ef[ 5], q1.y, g1);
        g0 = fmaf(Ef[ 6], p1.z, g0); g1 = fmaf(Ef[ 6], q1.z, g1);
        g0 = fmaf(Ef[ 7], p1.w, g0); g1 = fmaf(Ef[ 7], q1.w, g1);
        g0 = fmaf(Ef[ 8], p2.x, g0); g1 = fmaf(Ef[ 8], q2.x, g1);
        g0 = fmaf(Ef[ 9], p2.y, g0); g1 = fmaf(Ef[ 9], q2.y, g1);
        g0 = fmaf(Ef[10], p2.z, g0); g1 = fmaf(Ef[10], q2.z, g1);
        g0 = fmaf(Ef[11], p2.w, g0); g1 = fmaf(Ef[11], q2.w, g1);
        g0 = fmaf(Ef[12], p3.x, g0); g1 = fmaf(Ef[12], q3.x, g1);
        g0 = fmaf(Ef[13], p3.y, g0); g1 = fmaf(Ef[13], q3.y, g1);
        g0 = fmaf(Ef[14], p3.z, g0); g1 = fmaf(Ef[14], q3.z, g1);
        g0 = fmaf(Ef[15], p3.w, g0); g1 = fmaf(Ef[15], q3.w, g1);

        v = fmaf(leaky(g0), attn[2 * j],     v);
        v = fmaf(leaky(g1), attn[2 * j + 1], v);
    }

    const float p = __expf(v);
    const int pos = atomicAdd(rowpos + d, 1);
    SP[pos] = make_int2(s, __float_as_int(p));
}

// ---------------- Kernel 2 (fallback, round-4 proven): original order --------
__global__ __launch_bounds__(256) void edge_kernel_orig(
    const float* __restrict__ edge_attr, const int* __restrict__ src,
    const int* __restrict__ dst, const float* __restrict__ W1,
    const float* __restrict__ attn, const ushort16* __restrict__ Abf,
    int* __restrict__ rowpos, int2* __restrict__ SP, int E_)
{
    const int e = blockIdx.x * 256 + threadIdx.x;
    if (e >= E_) return;
    const int s = src[e];
    const int d = dst[e];

    uint32 Ad[32];
    {
        const uint4* Ap = (const uint4*)(Abf + (size_t)s * D);
#pragma unroll
        for (int t = 0; t < 8; t++) *(uint4*)(Ad + 4 * t) = Ap[t];
    }
    float Ef[16];
    {
        const float4* Ep = (const float4*)(edge_attr + (size_t)e * D_EDGE);
#pragma unroll
        for (int t = 0; t < 4; t++) *(float4*)(Ef + 4 * t) = Ep[t];
    }

    float v = 0.f;
#pragma unroll
    for (int j = 0; j < 32; ++j) {
        const float4* w0 = (const float4*)(W1 + (2 * j) * 80 + 64);
        const float4* w1 = (const float4*)(W1 + (2 * j + 1) * 80 + 64);
        float4 p0 = w0[0], p1 = w0[1], p2 = w0[2], p3 = w0[3];
        float4 q0 = w1[0], q1 = w1[1], q2 = w1[2], q3 = w1[3];
        float g0 = bf_lo(Ad[j]);
        float g1 = bf_hi(Ad[j]);
        g0 = fmaf(Ef[ 0], p0.x, g0); g1 = fmaf(Ef[ 0], q0.x, g1);
        g0 = fmaf(Ef[ 1], p0.y, g0); g1 = fmaf(Ef[ 1], q0.y, g1);
        g0 = fmaf(Ef[ 2], p0.z, g0); g1 = fmaf(Ef[ 2], q0.z, g1);
        g0 = fmaf(Ef[ 3], p0.w, g0); g1 = fmaf(Ef[ 3], q0.w, g1);
        g0 = fmaf(Ef[ 4], p1.x, g0); g1 = fmaf(Ef[ 4], q1.x, g1);
        g0 = fmaf(Ef[ 5], p1.y, g0); g1 = fmaf(Ef[ 5], q1.y, g1);
        g0 = fmaf(Ef[ 6], p1.z, g0); g1 = fmaf(Ef[ 6], q1.z, g1);
        g0 = fmaf(Ef[ 7], p1.w, g0); g1 = fmaf(Ef[ 7], q1.w, g1);
        g0 = fmaf(Ef[ 8], p2.x, g0); g1 = fmaf(Ef[ 8], q2.x, g1);
        g0 = fmaf(Ef[ 9], p2.y, g0); g1 = fmaf(Ef[ 9], q2.y, g1);
        g0 = fmaf(Ef[10], p2.z, g0); g1 = fmaf(Ef[10], q2.z, g1);
        g0 = fmaf(Ef[11], p2.w, g0); g1 = fmaf(Ef[11], q2.w, g1);
        g0 = fmaf(Ef[12], p3.x, g0); g1 = fmaf(Ef[12], q3.x, g1);
        g0 = fmaf(Ef[13], p3.y, g0); g1 = fmaf(Ef[13], q3.y, g1);
        g0 = fmaf(Ef[14], p3.z, g0); g1 = fmaf(Ef[14], q3.z, g1);
        g0 = fmaf(Ef[15], p3.w, g0); g1 = fmaf(Ef[15], q3.w, g1);
        v = fmaf(leaky(g0), attn[2 * j],     v);
        v = fmaf(leaky(g1), attn[2 * j + 1], v);
    }

    const float p = __expf(v);
    const int pos = atomicAdd(rowpos + d, 1);
    SP[pos] = make_int2(s, __float_as_int(p));
}

// ---------------- Kernel 3: per-node CSR aggregation (unchanged) -------------
__global__ __launch_bounds__(256) void agg_kernel(
    const ushort16* __restrict__ xtb, const int2* __restrict__ SP,
    const int* __restrict__ rowend, const float* __restrict__ bias,
    float* __restrict__ out, int N_)
{
    const int n    = blockIdx.x * 4 + (threadIdx.x >> 6);
    const int lane = threadIdx.x & 63;
    if (n >= N_) return;
    const int half = lane >> 5;
    const int c    = lane & 31;

    const int end   = rowend[n];
    const int start = n ? rowend[n - 1] : 0;
    const uint32* X = (const uint32*)xtb;

    float accx = 0.f, accy = 0.f, den = 0.f;
    int i = start;
    for (; i + 7 < end; i += 8) {
        int2 A0 = SP[i+0], A1 = SP[i+1], A2 = SP[i+2], A3 = SP[i+3];
        int2 A4 = SP[i+4], A5 = SP[i+5], A6 = SP[i+6], A7 = SP[i+7];
        int   r0 = half ? A1.x : A0.x;  float p0 = __int_as_float(half ? A1.y : A0.y);
        int   r1 = half ? A3.x : A2.x;  float p1 = __int_as_float(half ? A3.y : A2.y);
        int   r2 = half ? A5.x : A4.x;  float p2 = __int_as_float(half ? A5.y : A4.y);
        int   r3 = half ? A7.x : A6.x;  float p3 = __int_as_float(half ? A7.y : A6.y);
        uint32 u0 = X[(size_t)r0 * 32 + c];
        uint32 u1 = X[(size_t)r1 * 32 + c];
        uint32 u2 = X[(size_t)r2 * 32 + c];
        uint32 u3 = X[(size_t)r3 * 32 + c];
        accx = fmaf(p0, bf_lo(u0), accx); accy = fmaf(p0, bf_hi(u0), accy);
        accx = fmaf(p1, bf_lo(u1), accx); accy = fmaf(p1, bf_hi(u1), accy);
        accx = fmaf(p2, bf_lo(u2), accx); accy = fmaf(p2, bf_hi(u2), accy);
        accx = fmaf(p3, bf_lo(u3), accx); accy = fmaf(p3, bf_hi(u3), accy);
        den += (p0 + p1) + (p2 + p3);
    }
    for (; i < end; i++) {
        int2 a = SP[i];
        if (half == 0) {
            float p = __int_as_float(a.y);
            uint32 u = X[(size_t)a.x * 32 + c];
            accx = fmaf(p, bf_lo(u), accx);
            accy = fmaf(p, bf_hi(u), accy);
            den += p;
        }
    }
    accx += __shfl_xor(accx, 32, 64);
    accy += __shfl_xor(accy, 32, 64);
    den  += __shfl_xor(den,  32, 64);

    if (half == 0) {
        const float sc = den > 0.f ? 1.f / den : 0.f;
        const float2 bb = *(const float2*)(bias + 2 * c);
        float2 o;
        o.x = fmaf(accx, sc, bb.x);
        o.y = fmaf(accy, sc, bb.y);
        *(float2*)(out + (size_t)n * D + 2 * c) = o;
    }
}

extern "C" void kernel_launch(void* const* d_in, const int* in_sizes, int n_in,
                              void* d_out, int out_size, void* d_ws, size_t ws_size,
                              hipStream_t stream)
{
    const float* x         = (const float*)d_in[0];
    const float* edge_attr = (const float*)d_in[1];
    const int*   src       = (const int*)d_in[2];
    const int*   dst       = (const int*)d_in[3];
    const float* W1        = (const float*)d_in[4];
    const float* W2        = (const float*)d_in[5];
    const float* attn      = (const float*)d_in[6];
    const float* bias      = (const float*)d_in[7];
    float* out = (float*)d_out;

    const int N_ = in_sizes[0] / D;   // 100000
    const int E_ = in_sizes[2];       // 1280000
    const int N2 = 2 * N_;

    // layout: Abf | xtb | SP | REC(48B*E, sorted path only) | rowst2[2N] | cnt2[2N] | part
    char* w = (char*)d_ws;
    ushort16* Abf  = (ushort16*)w;  w += (size_t)N_ * D * sizeof(ushort16);
    ushort16* xtb  = (ushort16*)w;  w += (size_t)N_ * D * sizeof(ushort16);
    int2*     SP   = (int2*)w;      w += (size_t)E_ * sizeof(int2);
    uint4*    REC  = (uint4*)w;
    const size_t rec_bytes = (size_t)E_ * 48;
    const size_t fixed_tail = (size_t)N2 * 4 * 2 + 1024;   // rowst2 + cnt2 + part
    const size_t base_used  = (size_t)((char*)REC - (char*)d_ws);
    const bool   sorted = (base_used + rec_bytes + fixed_tail) <= ws_size;
    if (sorted) w += rec_bytes;
    int* rowst2 = (int*)w;          w += (size_t)N2 * sizeof(int);
    int* cnt2   = (int*)w;          w += (size_t)N2 * sizeof(int);
    int* part   = (int*)w;

    hipMemsetAsync(cnt2, 0, (size_t)N2 * sizeof(int), stream);

    const int NB = (N2 + 1023) / 1024;   // 196 (<=256 supported)

    hist2_kernel<<<(E_ + 255) / 256, 256, 0, stream>>>(dst, src, cnt2, N_, E_);
    scan1<<<NB, 256, 0, stream>>>(cnt2, part, N2);
    scan3<<<NB, 256, 0, stream>>>(cnt2, part, rowst2, N2, NB);

    node_kernel<<<(N_ + 63) / 64, 256, 0, stream>>>(x, W1, W2, Abf, xtb, N_);

    if (sorted) {
        scatter_kernel<<<(E_ + 255) / 256, 256, 0, stream>>>(
            edge_attr, src, dst, rowst2 + N_, REC, E_);
        edge_kernel_sorted<<<(E_ + 255) / 256, 256, 0, stream>>>(
            REC, W1, attn, Abf, rowst2, SP, E_);
    } else {
        edge_kernel_orig<<<(E_ + 255) / 256, 256, 0, stream>>>(
            edge_attr, src, dst, W1, attn, Abf, rowst2, SP, E_);
    }

    agg_kernel<<<(N_ + 3) / 4, 256, 0, stream>>>(xtb, SP, rowst2, bias, out, N_);
}

// Round 10
// 391.304 us; speedup vs baseline: 1.2880x; 1.2880x over previous
//
#include <hip/hip_runtime.h>

#define D 64          // D_IN == D_OUT
#define D_EDGE 16
#define NEG 0.01f

typedef unsigned int  uint32;
typedef unsigned short ushort16;

// leaky = max(t, 0.01t): exact for both signs, 2 VALU ops
__device__ __forceinline__ float leaky(float v) { return fmaxf(v, NEG * v); }

// fp32 -> bf16 (round-to-nearest-even), and back (exact)
__device__ __forceinline__ ushort16 f2bf(float f) {
    uint32 b = __float_as_uint(f);
    uint32 r = b + 0x7fffu + ((b >> 16) & 1u);
    return (ushort16)(r >> 16);
}
__device__ __forceinline__ float bf2f(ushort16 u) {
    return __uint_as_float(((uint32)u) << 16);
}
__device__ __forceinline__ float bf_lo(uint32 w) { return __uint_as_float(w << 16); }
__device__ __forceinline__ float bf_hi(uint32 w) { return __uint_as_float(w & 0xffff0000u); }
__device__ __forceinline__ uint32 pk(float a, float b) {
    return (uint32)f2bf(a) | ((uint32)f2bf(b) << 16);
}

// ---------------- Kernel 1: per-node precompute (round-4 proven) -------------
__global__ __launch_bounds__(256) void node_kernel(
    const float* __restrict__ x, const float* __restrict__ W1,
    const float* __restrict__ W2,
    ushort16* __restrict__ Abf, ushort16* __restrict__ xtb, int N_)
{
    __shared__ float xs[64][68];               // 17408 B; reused for output staging
    uint32* sA = (uint32*)&xs[0][0];
    uint32* sX = sA + 64 * 33;

    const int tid = threadIdx.x;
    const int b0  = blockIdx.x * 64;

    for (int idx = tid; idx < 64 * 16; idx += 256) {
        const int rr = idx >> 4, cc = idx & 15;
        float4 v = make_float4(0.f, 0.f, 0.f, 0.f);
        if (b0 + rr < N_) v = ((const float4*)(x + (size_t)(b0 + rr) * D))[cc];
        *(float4*)&xs[rr][cc * 4] = v;
    }
    __syncthreads();

    const int lane = tid & 63;
    const int q    = __builtin_amdgcn_readfirstlane(tid >> 6);

    float4 xr[16];
#pragma unroll
    for (int i = 0; i < 16; i++) xr[i] = *(const float4*)&xs[lane][4 * i];
    __syncthreads();

    float a_prev = 0.f, b_prev = 0.f;
#pragma unroll
    for (int kk = 0; kk < 16; kk++) {
        const int k = q * 16 + kk;
        const float4* w2r = (const float4*)(W2 + (size_t)k * 64);
        const float4* w1r = (const float4*)(W1 + (size_t)k * 80);
        float a = 0.f, b = 0.f;
#pragma unroll
        for (int j = 0; j < 16; j++) {
            float4 w = w2r[j];
            a += xr[j].x * w.x + xr[j].y * w.y + xr[j].z * w.z + xr[j].w * w.w;
            float4 u = w1r[j];
            b += xr[j].x * u.x + xr[j].y * u.y + xr[j].z * u.z + xr[j].w * u.w;
        }
        if (kk & 1) {
            const int pr = k >> 1;
            sX[lane * 33 + pr] = pk(a_prev, a);
            sA[lane * 33 + pr] = pk(b_prev, b);
        } else {
            a_prev = a; b_prev = b;
        }
    }
    __syncthreads();

    uint32* Au = (uint32*)Abf;
    uint32* Xu = (uint32*)xtb;
    const size_t gbase = (size_t)b0 * 32;
    for (int base = tid * 4; base < 2048; base += 1024) {
        const int nn = base >> 5, cc = base & 31;
        if (b0 + nn < N_) {
            const uint32* ra = sA + nn * 33 + cc;
            const uint32* rx = sX + nn * 33 + cc;
            *(uint4*)(Au + gbase + base) = make_uint4(ra[0], ra[1], ra[2], ra[3]);
            *(uint4*)(Xu + gbase + base) = make_uint4(rx[0], rx[1], rx[2], rx[3]);
        }
    }
}

// ---------------- CSR build: histogram WITH rank capture ----------------
// rank[e] = this edge's arrival order within its dst segment. The atomic's
// return value is free — it de-atomizes edge_kernel (pos = rowst[d]+rank[e]),
// removing 1.28M slow (~25.6 G/s) atomics from the gather-bound edge phase.
__global__ __launch_bounds__(256) void hist_kernel(
    const int* __restrict__ dst, int* __restrict__ cnt,
    int* __restrict__ rank, int E_)
{
    int i = blockIdx.x * 256 + threadIdx.x;
    if (i < E_) rank[i] = atomicAdd(cnt + dst[i], 1);
}

// block b reduces cnt[b*1024..+1023] -> part[b] (raw block sums)
__global__ __launch_bounds__(256) void scan1(
    const int* __restrict__ cnt, int* __restrict__ part, int N_)
{
    __shared__ int sm[256];
    const int b = blockIdx.x, t = threadIdx.x;
    const int i0 = b * 1024 + t * 4;
    int s = 0;
    if (i0     < N_) s += cnt[i0];
    if (i0 + 1 < N_) s += cnt[i0 + 1];
    if (i0 + 2 < N_) s += cnt[i0 + 2];
    if (i0 + 3 < N_) s += cnt[i0 + 3];
    sm[t] = s; __syncthreads();
    for (int off = 128; off > 0; off >>= 1) {
        if (t < off) sm[t] += sm[t + off];
        __syncthreads();
    }
    if (t == 0) part[b] = sm[0];
}

// block b: scans raw part[] in LDS (nb<=256) then writes exclusive prefix.
__global__ __launch_bounds__(256) void scan3(
    const int* __restrict__ cnt, const int* __restrict__ part,
    int* __restrict__ rowst, int N_, int nb)
{
    __shared__ int sp[256];
    __shared__ int sm[256];
    const int b = blockIdx.x, t = threadIdx.x;

    sp[t] = (t < nb) ? part[t] : 0;
    __syncthreads();
    for (int off = 1; off < 256; off <<= 1) {
        int a = (t >= off) ? sp[t - off] : 0;
        __syncthreads();
        sp[t] += a;
        __syncthreads();
    }
    const int pbase = (b > 0) ? sp[b - 1] : 0;

    const int i0 = b * 1024 + t * 4;
    int c0 = 0, c1 = 0, c2 = 0, c3 = 0;
    if (i0     < N_) c0 = cnt[i0];
    if (i0 + 1 < N_) c1 = cnt[i0 + 1];
    if (i0 + 2 < N_) c2 = cnt[i0 + 2];
    if (i0 + 3 < N_) c3 = cnt[i0 + 3];
    const int s = c0 + c1 + c2 + c3;
    sm[t] = s; __syncthreads();
    for (int off = 1; off < 256; off <<= 1) {
        int a = (t >= off) ? sm[t - off] : 0;
        __syncthreads();
        sm[t] += a;
        __syncthreads();
    }
    const int base = pbase + (sm[t] - s);
    if (i0     < N_) rowst[i0]     = base;
    if (i0 + 1 < N_) rowst[i0 + 1] = base + c0;
    if (i0 + 2 < N_) rowst[i0 + 2] = base + c0 + c1;
    if (i0 + 3 < N_) rowst[i0 + 3] = base + c0 + c1 + c2;
}

// ---------------- Kernel 2: edge logits, ONE LANE PER EDGE, NO ATOMICS -------
// Round-8 proven structure (118 us, VGPR 32); the bump atomicAdd is replaced
// by pos = rowst[d] + rank[e] (precomputed in hist). Removes 1.28M atomic
// ops (~40-50 us at the measured 25.6 G/s atomic rate) from this kernel.
__global__ __launch_bounds__(256) void edge_kernel(
    const float* __restrict__ edge_attr, const int* __restrict__ src,
    const int* __restrict__ dst, const float* __restrict__ W1,
    const float* __restrict__ attn, const ushort16* __restrict__ Abf,
    const int* __restrict__ rowst, const int* __restrict__ rank,
    int2* __restrict__ SP, int E_)
{
    const int e = blockIdx.x * 256 + threadIdx.x;
    if (e >= E_) return;

    const int s = src[e];
    const int d = dst[e];

    // this lane's A row: 64 bf16 = 32 packed dwords (128 B), random gather
    uint32 Ad[32];
    {
        const uint4* Ap = (const uint4*)(Abf + (size_t)s * D);
#pragma unroll
        for (int t = 0; t < 8; t++) *(uint4*)(Ad + 4 * t) = Ap[t];
    }
    // this lane's edge_attr row: 16 f32 (64 B), dense across lanes
    float Ef[16];
    {
        const float4* Ep = (const float4*)(edge_attr + (size_t)e * D_EDGE);
#pragma unroll
        for (int t = 0; t < 4; t++) *(float4*)(Ef + 4 * t) = Ep[t];
    }

    float v = 0.f;
#pragma unroll
    for (int j = 0; j < 32; ++j) {          // packed dword j -> channels 2j, 2j+1
        // wave-uniform weight rows (16B-aligned): scalar loads
        const float4* w0 = (const float4*)(W1 + (2 * j) * 80 + 64);
        const float4* w1 = (const float4*)(W1 + (2 * j + 1) * 80 + 64);
        float4 p0 = w0[0], p1 = w0[1], p2 = w0[2], p3 = w0[3];
        float4 q0 = w1[0], q1 = w1[1], q2 = w1[2], q3 = w1[3];

        float g0 = bf_lo(Ad[j]);            // A[s][2j]
        float g1 = bf_hi(Ad[j]);            // A[s][2j+1]

        g0 = fmaf(Ef[ 0], p0.x, g0); g1 = fmaf(Ef[ 0], q0.x, g1);
        g0 = fmaf(Ef[ 1], p0.y, g0); g1 = fmaf(Ef[ 1], q0.y, g1);
        g0 = fmaf(Ef[ 2], p0.z, g0); g1 = fmaf(Ef[ 2], q0.z, g1);
        g0 = fmaf(Ef[ 3], p0.w, g0); g1 = fmaf(Ef[ 3], q0.w, g1);
        g0 = fmaf(Ef[ 4], p1.x, g0); g1 = fmaf(Ef[ 4], q1.x, g1);
        g0 = fmaf(Ef[ 5], p1.y, g0); g1 = fmaf(Ef[ 5], q1.y, g1);
        g0 = fmaf(Ef[ 6], p1.z, g0); g1 = fmaf(Ef[ 6], q1.z, g1);
        g0 = fmaf(Ef[ 7], p1.w, g0); g1 = fmaf(Ef[ 7], q1.w, g1);
        g0 = fmaf(Ef[ 8], p2.x, g0); g1 = fmaf(Ef[ 8], q2.x, g1);
        g0 = fmaf(Ef[ 9], p2.y, g0); g1 = fmaf(Ef[ 9], q2.y, g1);
        g0 = fmaf(Ef[10], p2.z, g0); g1 = fmaf(Ef[10], q2.z, g1);
        g0 = fmaf(Ef[11], p2.w, g0); g1 = fmaf(Ef[11], q2.w, g1);
        g0 = fmaf(Ef[12], p3.x, g0); g1 = fmaf(Ef[12], q3.x, g1);
        g0 = fmaf(Ef[13], p3.y, g0); g1 = fmaf(Ef[13], q3.y, g1);
        g0 = fmaf(Ef[14], p3.z, g0); g1 = fmaf(Ef[14], q3.z, g1);
        g0 = fmaf(Ef[15], p3.w, g0); g1 = fmaf(Ef[15], q3.w, g1);

        v = fmaf(leaky(g0), attn[2 * j],     v);
        v = fmaf(leaky(g1), attn[2 * j + 1], v);
    }

    const float p = __expf(v);
    const int pos = rowst[d] + rank[e];     // unique slot, no atomic
    SP[pos] = make_int2(s, __float_as_int(p));
}

// ---------------- Kernel 3: per-node CSR aggregation + normalize + bias ------
// rowst is now a pure exclusive prefix (never bumped): start = rowst[n],
// end = rowst[n+1] (E_ for the last node).
__global__ __launch_bounds__(256) void agg_kernel(
    const ushort16* __restrict__ xtb, const int2* __restrict__ SP,
    const int* __restrict__ rowst, const float* __restrict__ bias,
    float* __restrict__ out, int N_, int E_)
{
    const int n    = blockIdx.x * 4 + (threadIdx.x >> 6);
    const int lane = threadIdx.x & 63;
    if (n >= N_) return;
    const int half = lane >> 5;
    const int c    = lane & 31;

    const int start = rowst[n];
    const int end   = (n + 1 < N_) ? rowst[n + 1] : E_;
    const uint32* X = (const uint32*)xtb;    // dword idx = row*32 + c

    float accx = 0.f, accy = 0.f, den = 0.f;
    int i = start;
    for (; i + 7 < end; i += 8) {
        int2 A0 = SP[i+0], A1 = SP[i+1], A2 = SP[i+2], A3 = SP[i+3];
        int2 A4 = SP[i+4], A5 = SP[i+5], A6 = SP[i+6], A7 = SP[i+7];
        int   r0 = half ? A1.x : A0.x;  float p0 = __int_as_float(half ? A1.y : A0.y);
        int   r1 = half ? A3.x : A2.x;  float p1 = __int_as_float(half ? A3.y : A2.y);
        int   r2 = half ? A5.x : A4.x;  float p2 = __int_as_float(half ? A5.y : A4.y);
        int   r3 = half ? A7.x : A6.x;  float p3 = __int_as_float(half ? A7.y : A6.y);
        uint32 u0 = X[(size_t)r0 * 32 + c];
        uint32 u1 = X[(size_t)r1 * 32 + c];
        uint32 u2 = X[(size_t)r2 * 32 + c];
        uint32 u3 = X[(size_t)r3 * 32 + c];
        accx = fmaf(p0, bf_lo(u0), accx); accy = fmaf(p0, bf_hi(u0), accy);
        accx = fmaf(p1, bf_lo(u1), accx); accy = fmaf(p1, bf_hi(u1), accy);
        accx = fmaf(p2, bf_lo(u2), accx); accy = fmaf(p2, bf_hi(u2), accy);
        accx = fmaf(p3, bf_lo(u3), accx); accy = fmaf(p3, bf_hi(u3), accy);
        den += (p0 + p1) + (p2 + p3);
    }
    for (; i < end; i++) {                 // <=7 leftovers: low half only
        int2 a = SP[i];
        if (half == 0) {
            float p = __int_as_float(a.y);
            uint32 u = X[(size_t)a.x * 32 + c];
            accx = fmaf(p, bf_lo(u), accx);
            accy = fmaf(p, bf_hi(u), accy);
            den += p;
        }
    }
    accx += __shfl_xor(accx, 32, 64);
    accy += __shfl_xor(accy, 32, 64);
    den  += __shfl_xor(den,  32, 64);

    if (half == 0) {
        const float sc = den > 0.f ? 1.f / den : 0.f;
        const float2 bb = *(const float2*)(bias + 2 * c);
        float2 o;
        o.x = fmaf(accx, sc, bb.x);
        o.y = fmaf(accy, sc, bb.y);
        *(float2*)(out + (size_t)n * D + 2 * c) = o;
    }
}

extern "C" void kernel_launch(void* const* d_in, const int* in_sizes, int n_in,
                              void* d_out, int out_size, void* d_ws, size_t ws_size,
                              hipStream_t stream)
{
    const float* x         = (const float*)d_in[0];
    const float* edge_attr = (const float*)d_in[1];
    const int*   src       = (const int*)d_in[2];
    const int*   dst       = (const int*)d_in[3];
    const float* W1        = (const float*)d_in[4];
    const float* W2        = (const float*)d_in[5];
    const float* attn      = (const float*)d_in[6];
    const float* bias      = (const float*)d_in[7];
    float* out = (float*)d_out;

    const int N_ = in_sizes[0] / D;   // 100000
    const int E_ = in_sizes[2];       // 1280000

    // workspace (~42 MB):
    //   Abf[N*64] bf16 | xtb[N*64] bf16 | SP[E] int2 | rank[E] | rowst[N] | cnt[N] | part
    char* w = (char*)d_ws;
    ushort16* Abf  = (ushort16*)w;  w += (size_t)N_ * D * sizeof(ushort16);
    ushort16* xtb  = (ushort16*)w;  w += (size_t)N_ * D * sizeof(ushort16);
    int2*     SP   = (int2*)w;      w += (size_t)E_ * sizeof(int2);
    int*      rank = (int*)w;       w += (size_t)E_ * sizeof(int);
    int*      rowst= (int*)w;       w += (size_t)N_ * sizeof(int);
    int*      cnt  = (int*)w;       w += (size_t)N_ * sizeof(int);
    int*      part = (int*)w;

    hipMemsetAsync(cnt, 0, (size_t)N_ * sizeof(int), stream);

    const int NB = (N_ + 1023) / 1024;   // 98 (<=256 supported)

    hist_kernel<<<(E_ + 255) / 256, 256, 0, stream>>>(dst, cnt, rank, E_);
    scan1<<<NB, 256, 0, stream>>>(cnt, part, N_);
    scan3<<<NB, 256, 0, stream>>>(cnt, part, rowst, N_, NB);

    node_kernel<<<(N_ + 63) / 64, 256, 0, stream>>>(x, W1, W2, Abf, xtb, N_);

    edge_kernel<<<(E_ + 255) / 256, 256, 0, stream>>>(edge_attr, src, dst, W1,
                                                      attn, Abf, rowst, rank, SP, E_);

    agg_kernel<<<(N_ + 3) / 4, 256, 0, stream>>>(xtb, SP, rowst, bias, out, N_, E_);
}